// Round 8
// baseline (319.872 us; speedup 1.0000x reference)
//
#include <hip/hip_runtime.h>
#include <hip/hip_bf16.h>
#include <stdint.h>

typedef __attribute__((ext_vector_type(8))) __bf16 bf16x8;
typedef __attribute__((ext_vector_type(4))) float floatx4;

#define EPS 1e-5f

static __device__ __forceinline__ unsigned short f2bf(float f) {
    union { float f; unsigned int u; } x; x.f = f;
    unsigned int r = x.u + 0x7fffu + ((x.u >> 16) & 1u);
    return (unsigned short)(r >> 16);
}
static __device__ __forceinline__ float bf2f_lo(unsigned int u) {
    union { unsigned int u; float f; } x; x.u = u << 16; return x.f;
}
static __device__ __forceinline__ float bf2f_hi(unsigned int u) {
    union { unsigned int u; float f; } x; x.u = u & 0xffff0000u; return x.f;
}

struct Params {
    const float* x_in;
    const int*   knn;
    const float* w1s[3];
    const float* w2s[3];
    const float* vws[2];
    const float* b1s[3];
    const float* b2s[3];
    const float* gs[3];
    const float* bes[3];
    const float* ms[3];
    const float* vvs[3];
    const float* vbb[2];
    const float* vgg[2];
    const float* vbt[2];
    const float* vmm[2];
    const float* vva[2];
    unsigned short* wpk;   // per-batch packed weights, 425984 shorts/batch
    unsigned short* vb0;
    unsigned short* vb1;
    int* ctr;              // 3 barriers x 8 batches x 16-int stride
    float* xf;
};

// batch-local barrier: 64 blocks arrive. Release flushes this XCD's L2
// (covers all waves' stores; __syncthreads drains vmcnt first); acquire
// invalidates caches before readers proceed. Bounded spin: no hard hang.
static __device__ __forceinline__ void bbar(int* c) {
    __syncthreads();
    if (threadIdx.x == 0) {
        __hip_atomic_fetch_add(c, 1, __ATOMIC_RELEASE, __HIP_MEMORY_SCOPE_AGENT);
        int spins = 0;
        while (__hip_atomic_load(c, __ATOMIC_ACQUIRE, __HIP_MEMORY_SCOPE_AGENT) < 64
               && spins < (1 << 26)) {
            ++spins;
            __builtin_amdgcn_s_sleep(2);
        }
    }
    __syncthreads();
}

// ---- FFN: xf32 += BN(relu(x@W1+b1)@W2+b2)  (4 x 128-hid slices) ----
static __device__ __forceinline__ void ffn_block(
    const Params& P, const unsigned short* WPK, int t, bool last,
    unsigned short* xt, float* xf32, uint2* ht2,
    int p0, int w, int q, int ln, int sw)
{
    const floatx4 zero = {0.f, 0.f, 0.f, 0.f};
    floatx4 acc2[4];
#pragma unroll
    for (int i = 0; i < 4; ++i) acc2[i] = zero;
    const unsigned short* W1 = WPK + t * 65536;
    const unsigned short* W2 = WPK + 196608 + t * 65536;
    const float* b1 = P.b1s[t];

#pragma unroll
    for (int hf = 0; hf < 4; ++hf) {
        floatx4 acc1[4];
#pragma unroll
        for (int i = 0; i < 4; ++i) acc1[i] = zero;
        const unsigned short* a1 = W1 + hf * 16384 + w * 2048 + q * 128 + ln * 8;
#pragma unroll
        for (int ks = 0; ks < 4; ++ks) {
            bf16x8 af = *(const bf16x8*)(a1 + ks * 512);
#pragma unroll
            for (int nt = 0; nt < 4; ++nt) {
                bf16x8 bfr = *(const bf16x8*)&xt[((16 * nt + ln) * 16 + ((4 * ks + q) ^ sw)) * 8];
                acc1[nt] = __builtin_amdgcn_mfma_f32_16x16x32_bf16(af, bfr, acc1[nt], 0, 0, 0);
            }
        }
        // epilogue1: +b1, relu, pack -> ht
        {
            const int hid0 = 16 * w + 4 * q;
            const int gh   = 128 * hf + hid0;
            const float bv0 = b1[gh], bv1 = b1[gh + 1];
            const float bv2 = b1[gh + 2], bv3 = b1[gh + 3];
            const int c16  = hid0 >> 3;
            const int half = q & 1;
#pragma unroll
            for (int nt = 0; nt < 4; ++nt) {
                const int pt = 16 * nt + ln;
                float v0 = acc1[nt][0] + bv0; v0 = v0 > 0.f ? v0 : 0.f;
                float v1 = acc1[nt][1] + bv1; v1 = v1 > 0.f ? v1 : 0.f;
                float v2 = acc1[nt][2] + bv2; v2 = v2 > 0.f ? v2 : 0.f;
                float v3 = acc1[nt][3] + bv3; v3 = v3 > 0.f ? v3 : 0.f;
                uint2 pk;
                pk.x = (unsigned int)f2bf(v0) | ((unsigned int)f2bf(v1) << 16);
                pk.y = (unsigned int)f2bf(v2) | ((unsigned int)f2bf(v3) << 16);
                ht2[(pt * 16 + (c16 ^ (pt & 7))) * 2 + half] = pk;
            }
        }
        __syncthreads();
        const unsigned short* b2b = W2 + hf * 16384 + w * 2048 + q * 128 + ln * 8;
#pragma unroll
        for (int ks = 0; ks < 4; ++ks) {
            bf16x8 bw = *(const bf16x8*)(b2b + ks * 512);
#pragma unroll
            for (int mt = 0; mt < 4; ++mt) {
                bf16x8 ah = *(const bf16x8*)&ht2[((16 * mt + ln) * 16 + ((4 * ks + q) ^ sw)) * 2];
                acc2[mt] = __builtin_amdgcn_mfma_f32_16x16x32_bf16(ah, bw, acc2[mt], 0, 0, 0);
            }
        }
        __syncthreads();
    }
    // epilogue2: BN + residual (fp32 base in LDS)
    {
        const float* b2   = P.b2s[t];
        const float* gam  = P.gs[t];
        const float* bet  = P.bes[t];
        const float* mean = P.ms[t];
        const float* var  = P.vvs[t];
        const int c = 16 * w + ln;
        const float scv = gam[c] * rsqrtf(var[c] + EPS);
        const float off = (b2[c] - mean[c]) * scv + bet[c];
#pragma unroll
        for (int mt = 0; mt < 4; ++mt) {
#pragma unroll
            for (int r = 0; r < 4; ++r) {
                const int rl = 16 * mt + 4 * q + r;
                float xn = xf32[rl * 128 + c] + acc2[mt][r] * scv + off;
                if (last) {
                    P.xf[(size_t)(p0 + rl) * 128 + c] = xn;
                } else {
                    xf32[rl * 128 + c] = xn;
                    xt[(rl * 16 + ((c >> 3) ^ (rl & 7))) * 8 + (c & 7)] = f2bf(xn);
                }
            }
        }
    }
}

// ---- VFR linear: VbOut = bf16(x @ Wv + vb) ----
static __device__ __forceinline__ void vfr_block(
    const Params& P, const unsigned short* WPK, int tv,
    unsigned short* xt, unsigned short* VbOut,
    int p0, int w, int q, int ln, int sw)
{
    __syncthreads();
    const floatx4 zero = {0.f, 0.f, 0.f, 0.f};
    const unsigned short* VT = WPK + 393216 + tv * 16384;
    floatx4 acc[4];
#pragma unroll
    for (int i = 0; i < 4; ++i) acc[i] = zero;
    const unsigned short* bb2 = VT + w * 2048 + q * 128 + ln * 8;
#pragma unroll
    for (int ks = 0; ks < 4; ++ks) {
        bf16x8 bw = *(const bf16x8*)(bb2 + ks * 512);
#pragma unroll
        for (int mt = 0; mt < 4; ++mt) {
            bf16x8 ax = *(const bf16x8*)&xt[((16 * mt + ln) * 16 + ((4 * ks + q) ^ sw)) * 8];
            acc[mt] = __builtin_amdgcn_mfma_f32_16x16x32_bf16(ax, bw, acc[mt], 0, 0, 0);
        }
    }
    const int c = 16 * w + ln;
    const float bia = P.vbb[tv][c];
#pragma unroll
    for (int mt = 0; mt < 4; ++mt)
#pragma unroll
        for (int r = 0; r < 4; ++r) {
            const int pt = 16 * mt + 4 * q + r;
            VbOut[(size_t)(p0 + pt) * 128 + c] = f2bf(acc[mt][r] + bia);
        }
}

// ---- edge: x += BN(max_k V[knn] - V[self]); x stays in LDS ----
static __device__ __forceinline__ void edge_block(
    const Params& P, int te, const unsigned short* VbIn,
    unsigned short* xt, float* xf32,
    int p0, int batch, int w, int q, int ln)
{
    const int ch0 = ln * 8;
    float4 ga = *(const float4*)(P.vgg[te] + ch0), gb = *(const float4*)(P.vgg[te] + ch0 + 4);
    float4 ba = *(const float4*)(P.vbt[te] + ch0), bb = *(const float4*)(P.vbt[te] + ch0 + 4);
    float4 ma = *(const float4*)(P.vmm[te] + ch0), mb = *(const float4*)(P.vmm[te] + ch0 + 4);
    float4 va = *(const float4*)(P.vva[te] + ch0), vb = *(const float4*)(P.vva[te] + ch0 + 4);
    float sc[8], of[8];
    const float gv[8] = {ga.x, ga.y, ga.z, ga.w, gb.x, gb.y, gb.z, gb.w};
    const float bv[8] = {ba.x, ba.y, ba.z, ba.w, bb.x, bb.y, bb.z, bb.w};
    const float mv[8] = {ma.x, ma.y, ma.z, ma.w, mb.x, mb.y, mb.z, mb.w};
    const float vv[8] = {va.x, va.y, va.z, va.w, vb.x, vb.y, vb.z, vb.w};
#pragma unroll
    for (int j = 0; j < 8; ++j) {
        sc[j] = gv[j] * rsqrtf(vv[j] + EPS);
        of[j] = bv[j] - mv[j] * sc[j];
    }
#pragma unroll
    for (int it = 0; it < 2; ++it) {
        const int pl = it * 32 + w * 4 + q;
        const int p  = p0 + pl;
        uint4 sv = *(const uint4*)(VbIn + (size_t)p * 128 + ch0);
        const int* kp = P.knn + (size_t)p * 16;
        int4 ka = *(const int4*)(kp);
        int4 kb = *(const int4*)(kp + 4);
        int4 kc = *(const int4*)(kp + 8);
        int4 kd = *(const int4*)(kp + 12);
        const unsigned short* vbase = VbIn + ((size_t)batch << 19) + ch0;
        float m[8];
#pragma unroll
        for (int j = 0; j < 8; ++j) m[j] = -3.4e38f;
#define GATH(IDX) { uint4 u4 = *(const uint4*)(vbase + ((size_t)(IDX) << 7));      \
        m[0] = fmaxf(m[0], bf2f_lo(u4.x)); m[1] = fmaxf(m[1], bf2f_hi(u4.x)); \
        m[2] = fmaxf(m[2], bf2f_lo(u4.y)); m[3] = fmaxf(m[3], bf2f_hi(u4.y)); \
        m[4] = fmaxf(m[4], bf2f_lo(u4.z)); m[5] = fmaxf(m[5], bf2f_hi(u4.z)); \
        m[6] = fmaxf(m[6], bf2f_lo(u4.w)); m[7] = fmaxf(m[7], bf2f_hi(u4.w)); }
        GATH(ka.x) GATH(ka.y) GATH(ka.z) GATH(ka.w)
        GATH(kb.x) GATH(kb.y) GATH(kb.z) GATH(kb.w)
        GATH(kc.x) GATH(kc.y) GATH(kc.z) GATH(kc.w)
        GATH(kd.x) GATH(kd.y) GATH(kd.z) GATH(kd.w)
#undef GATH
        float s_[8];
        s_[0] = bf2f_lo(sv.x); s_[1] = bf2f_hi(sv.x);
        s_[2] = bf2f_lo(sv.y); s_[3] = bf2f_hi(sv.y);
        s_[4] = bf2f_lo(sv.z); s_[5] = bf2f_hi(sv.z);
        s_[6] = bf2f_lo(sv.w); s_[7] = bf2f_hi(sv.w);
        float* xr = &xf32[pl * 128 + ch0];
        float4 x0 = *(const float4*)xr;
        float4 x1 = *(const float4*)(xr + 4);
        float xo[8] = {x0.x, x0.y, x0.z, x0.w, x1.x, x1.y, x1.z, x1.w};
        float xn[8];
        unsigned int pw[8];
#pragma unroll
        for (int j = 0; j < 8; ++j) {
            xn[j] = xo[j] + (m[j] - s_[j]) * sc[j] + of[j];
            pw[j] = (unsigned int)f2bf(xn[j]);
        }
        *(float4*)xr       = make_float4(xn[0], xn[1], xn[2], xn[3]);
        *(float4*)(xr + 4) = make_float4(xn[4], xn[5], xn[6], xn[7]);
        uint4 pk;
        pk.x = pw[0] | (pw[1] << 16);
        pk.y = pw[2] | (pw[3] << 16);
        pk.z = pw[4] | (pw[5] << 16);
        pk.w = pw[6] | (pw[7] << 16);
        *(uint4*)&xt[(pl * 16 + (ln ^ (pl & 7))) * 8] = pk;
    }
}

// ---- the persistent fused kernel: 512 blocks x 512 thr, 2 blocks/CU ----
__global__ __launch_bounds__(512, 4) void fused(Params P) {
    __shared__ __align__(16) unsigned short xt[8192];   // 16 KB bf16 x tile (XOR)
    __shared__ __align__(16) float xf32[8192];          // 32 KB fp32 x (persistent)
    __shared__ __align__(16) uint2 ht2[2048];           // 16 KB h tile
    const int tid   = threadIdx.x;
    const int lane  = tid & 63;
    const int w     = tid >> 6;
    const int q     = lane >> 4;
    const int ln    = lane & 15;
    const int sw    = ln & 7;
    const int phys  = blockIdx.x;
    const int batch = phys & 7;
    const int blk   = phys >> 3;
    const int p0    = batch * 4096 + blk * 64;
    unsigned short* WPK = P.wpk + (size_t)batch * 425984;

    // ---- phase 0: per-batch weight pack (64 blocks share) ----
    {
        const int bt = blk * 512 + tid;   // 0..32767 within batch
#pragma unroll
        for (int t = 0; t < 3; ++t) {
            const float* s1 = P.w1s[t];
            unsigned short* d1 = WPK + t * 65536;
            for (int idx = bt; idx < 65536; idx += 32768) {
                int h = idx & 511, k = idx >> 9;
                int hf = h >> 7, ww = (h >> 4) & 7, l2 = h & 15;
                int ks = (k >> 5) & 3, qq = (k >> 3) & 3, j = k & 7;
                d1[hf * 16384 + ww * 2048 + ks * 512 + qq * 128 + l2 * 8 + j] = f2bf(s1[idx]);
            }
            const float* s2 = P.w2s[t];
            unsigned short* d2 = WPK + 196608 + t * 65536;
            for (int idx = bt; idx < 65536; idx += 32768) {
                int c = idx & 127, h = idx >> 7;
                int hf = h >> 7, ks = (h >> 5) & 3, qq = (h >> 3) & 3, j = h & 7;
                int ww = c >> 4, l2 = c & 15;
                d2[hf * 16384 + ww * 2048 + ks * 512 + qq * 128 + l2 * 8 + j] = f2bf(s2[idx]);
            }
        }
#pragma unroll
        for (int t = 0; t < 2; ++t) {
            const float* svv = P.vws[t];
            unsigned short* dv = WPK + 393216 + t * 16384;
            for (int idx = bt; idx < 16384; idx += 32768) {
                int c = idx & 127, k = idx >> 7;
                int ks = (k >> 5) & 3, qq = (k >> 3) & 3, j = k & 7;
                int ww = c >> 4, l2 = c & 15;
                dv[ww * 2048 + ks * 512 + qq * 128 + l2 * 8 + j] = f2bf(svv[idx]);
            }
        }
    }

    // ---- LOADX: x_in -> xf32 + xt ----
    {
        const int r = tid >> 3, cc = tid & 7;
        const float4* src = (const float4*)(P.x_in + (size_t)(p0 + r) * 128 + cc * 16);
        float4* dstf = (float4*)&xf32[r * 128 + cc * 16];
#pragma unroll
        for (int i = 0; i < 2; ++i) {
            float4 a = src[2 * i], b = src[2 * i + 1];
            dstf[2 * i]     = a;
            dstf[2 * i + 1] = b;
            int kq = cc * 2 + i;
            uint4 pk;
            pk.x = (unsigned int)f2bf(a.x) | ((unsigned int)f2bf(a.y) << 16);
            pk.y = (unsigned int)f2bf(a.z) | ((unsigned int)f2bf(a.w) << 16);
            pk.z = (unsigned int)f2bf(b.x) | ((unsigned int)f2bf(b.y) << 16);
            pk.w = (unsigned int)f2bf(b.z) | ((unsigned int)f2bf(b.w) << 16);
            *(uint4*)&xt[(r * 16 + (kq ^ (r & 7))) * 8] = pk;
        }
    }

    bbar(P.ctr + batch * 16);                    // pack done (batch-local)
    ffn_block(P, WPK, 0, false, xt, xf32, ht2, p0, w, q, ln, sw);
    vfr_block(P, WPK, 0, xt, P.vb0, p0, w, q, ln, sw);
    bbar(P.ctr + (8 + batch) * 16);              // Vb0 complete for batch
    edge_block(P, 0, P.vb0, xt, xf32, p0, batch, w, q, ln);
    __syncthreads();
    ffn_block(P, WPK, 1, false, xt, xf32, ht2, p0, w, q, ln, sw);
    vfr_block(P, WPK, 1, xt, P.vb1, p0, w, q, ln, sw);
    bbar(P.ctr + (16 + batch) * 16);             // Vb1 complete for batch
    edge_block(P, 1, P.vb1, xt, xf32, p0, batch, w, q, ln);
    __syncthreads();
    ffn_block(P, WPK, 2, true, xt, xf32, ht2, p0, w, q, ln, sw);
}

// ---------------- launch ----------------
extern "C" void kernel_launch(void* const* d_in, const int* in_sizes, int n_in,
                              void* d_out, int out_size, void* d_ws, size_t ws_size,
                              hipStream_t stream)
{
    Params p;
    p.x_in = (const float*)d_in[0];
    p.knn  = (const int*)d_in[1];
    const float* w1  = (const float*)d_in[2];
    const float* b1  = (const float*)d_in[3];
    const float* w2  = (const float*)d_in[4];
    const float* b2  = (const float*)d_in[5];
    const float* g0  = (const float*)d_in[6];
    const float* be0 = (const float*)d_in[7];
    const float* m0p = (const float*)d_in[8];
    const float* v0p = (const float*)d_in[9];
    const float* vw  = (const float*)d_in[10];
    const float* vbp = (const float*)d_in[11];
    const float* vgp = (const float*)d_in[12];
    const float* vbe = (const float*)d_in[13];
    const float* vmp = (const float*)d_in[14];
    const float* vvp = (const float*)d_in[15];
    const float* fw1 = (const float*)d_in[16];
    const float* fb1 = (const float*)d_in[17];
    const float* fw2 = (const float*)d_in[18];
    const float* fb2 = (const float*)d_in[19];
    const float* fg  = (const float*)d_in[20];
    const float* fbe = (const float*)d_in[21];
    const float* fm  = (const float*)d_in[22];
    const float* fv  = (const float*)d_in[23];

    p.w1s[0] = w1;  p.w1s[1] = fw1; p.w1s[2] = fw1 + 65536;
    p.w2s[0] = w2;  p.w2s[1] = fw2; p.w2s[2] = fw2 + 65536;
    p.vws[0] = vw;  p.vws[1] = vw + 16384;
    p.b1s[0] = b1;  p.b1s[1] = fb1; p.b1s[2] = fb1 + 512;
    p.b2s[0] = b2;  p.b2s[1] = fb2; p.b2s[2] = fb2 + 128;
    p.gs[0]  = g0;  p.gs[1]  = fg;  p.gs[2]  = fg + 128;
    p.bes[0] = be0; p.bes[1] = fbe; p.bes[2] = fbe + 128;
    p.ms[0]  = m0p; p.ms[1]  = fm;  p.ms[2]  = fm + 128;
    p.vvs[0] = v0p; p.vvs[1] = fv;  p.vvs[2] = fv + 128;
    p.vbb[0] = vbp; p.vbb[1] = vbp + 128;
    p.vgg[0] = vgp; p.vgg[1] = vgp + 128;
    p.vbt[0] = vbe; p.vbt[1] = vbe + 128;
    p.vmm[0] = vmp; p.vmm[1] = vmp + 128;
    p.vva[0] = vvp; p.vva[1] = vvp + 128;

    char* ws = (char*)d_ws;
    p.vb0 = (unsigned short*)ws;                          // 8 MiB
    p.vb1 = (unsigned short*)(ws + (size_t)(8 << 20));    // 8 MiB
    p.wpk = (unsigned short*)(ws + (size_t)(16 << 20));   // 8 x 832 KiB
    p.ctr = (int*)(ws + (size_t)(24 << 20));              // barrier counters
    p.xf  = (float*)d_out;

    hipMemsetAsync(p.ctr, 0, 3 * 8 * 16 * sizeof(int), stream);
    fused<<<dim3(512), dim3(512), 0, stream>>>(p);
}

// Round 9
// 188.995 us; speedup vs baseline: 1.6925x; 1.6925x over previous
//
#include <hip/hip_runtime.h>
#include <hip/hip_bf16.h>
#include <stdint.h>

typedef __attribute__((ext_vector_type(8))) __bf16 bf16x8;
typedef __attribute__((ext_vector_type(4))) float floatx4;

#define EPS 1e-5f

static __device__ __forceinline__ unsigned short f2bf(float f) {
    union { float f; unsigned int u; } x; x.f = f;
    unsigned int r = x.u + 0x7fffu + ((x.u >> 16) & 1u);
    return (unsigned short)(r >> 16);
}
static __device__ __forceinline__ float bf2f_lo(unsigned int u) {
    union { unsigned int u; float f; } x; x.u = u << 16; return x.f;
}
static __device__ __forceinline__ float bf2f_hi(unsigned int u) {
    union { unsigned int u; float f; } x; x.u = u & 0xffff0000u; return x.f;
}

struct Params {
    const float* x_in;
    const int*   knn;
    const float* w1s[3];
    const float* w2s[3];
    const float* vws[2];
    unsigned short* W1P[3];
    unsigned short* W2P[3];
    unsigned short* VTP[2];
    const float* b1s[3];
    const float* b2s[3];
    const float* gs[3];
    const float* bes[3];
    const float* ms[3];
    const float* vvs[3];
    const float* vbb[2];
    const float* vgg[2];
    const float* vbt[2];
    const float* vmm[2];
    const float* vva[2];
    float* xf;
};

// ---------------- pack weights fragment-major (bf16) for 4-wave blocks -----
// W1P: dst = hf*16384 + w*4096 + mt*2048 + ks*512 + q*128 + ln*8 + j
//      holds W1[k=32ks+8q+j][h=128hf+32w+16mt+ln]   (src [128][512])
// W2P: dst = hf*16384 + w*4096 + nt*2048 + ks*512 + q*128 + ln*8 + j
//      holds W2[h=128hf+32ks+8q+j][c=32w+16nt+ln]   (src [512][128])
// VTP: dst = w*4096 + nt*2048 + ks*512 + q*128 + ln*8 + j
//      holds Wv[k=32ks+8q+j][c=32w+16nt+ln]         (src [128][128])
__global__ __launch_bounds__(256) void pack_weights(Params P) {
    const int gtid = blockIdx.x * 256 + threadIdx.x;
    const int GT   = gridDim.x * 256;
#pragma unroll
    for (int t = 0; t < 3; ++t) {
        const float* s1 = P.w1s[t];
        unsigned short* d1 = P.W1P[t];
        for (int idx = gtid; idx < 65536; idx += GT) {
            int h = idx & 511, k = idx >> 9;
            int hf = h >> 7, w = (h >> 5) & 3, mt = (h >> 4) & 1, ln = h & 15;
            int ks = k >> 5, q = (k >> 3) & 3, j = k & 7;
            d1[hf * 16384 + w * 4096 + mt * 2048 + ks * 512 + q * 128 + ln * 8 + j]
                = f2bf(s1[idx]);
        }
        const float* s2 = P.w2s[t];
        unsigned short* d2 = P.W2P[t];
        for (int idx = gtid; idx < 65536; idx += GT) {
            int c = idx & 127, h = idx >> 7;
            int hf = h >> 7, hk = h & 127;
            int ks = hk >> 5, q = (hk >> 3) & 3, j = hk & 7;
            int w = c >> 5, nt = (c >> 4) & 1, ln = c & 15;
            d2[hf * 16384 + w * 4096 + nt * 2048 + ks * 512 + q * 128 + ln * 8 + j]
                = f2bf(s2[idx]);
        }
    }
#pragma unroll
    for (int t = 0; t < 2; ++t) {
        const float* sv = P.vws[t];
        unsigned short* dv = P.VTP[t];
        for (int idx = gtid; idx < 16384; idx += GT) {
            int c = idx & 127, k = idx >> 7;
            int ks = k >> 5, q = (k >> 3) & 3, j = k & 7;
            int w = c >> 5, nt = (c >> 4) & 1, ln = c & 15;
            dv[w * 4096 + nt * 2048 + ks * 512 + q * 128 + ln * 8 + j] = f2bf(sv[idx]);
        }
    }
}

// ---------------- fused stage (256 thr = 4 waves, 32 points/block) ---------
// LDS 24 KB: xt (bf16 x tile, 8 KB, XOR swizzle) + buf 16 KB
//   (time-shared: fp32 x staging during LOADX/edge -> then h tile for FFN).
// Residual x lives in 16 fp32 VGPRs/thread (epilogue layout).
// 1024 blocks; batch = phys&7 => XCD i handles batch i (L2-local gathers).
template <int LOADX, int TE, int TF, int TV>
__global__ __launch_bounds__(256, 4)
void stage(Params P, const float* __restrict__ xold_g,
           const unsigned short* __restrict__ VbIn,
           unsigned short* __restrict__ VbOut)
{
    __shared__ __align__(16) unsigned short xt[4096];   // 8 KB
    __shared__ __align__(16) float buf_f[4096];         // 16 KB (hx | ht)
    const int tid   = threadIdx.x;
    const int lane  = tid & 63;
    const int w     = tid >> 6;      // wave 0..3
    const int q     = lane >> 4;
    const int ln    = lane & 15;
    const int sw    = ln & 7;
    const int phys  = blockIdx.x;
    const int batch = phys & 7;
    const int blk   = phys >> 3;
    const int p0    = (batch << 12) + (blk << 5);
    const floatx4 zero = {0.f, 0.f, 0.f, 0.f};
    uint2* ht2 = (uint2*)buf_f;

    if constexpr (LOADX) {
        const int r = tid >> 3, cc = tid & 7;   // r 0..31, cc 0..7
        const float4* src = (const float4*)(xold_g + (size_t)(p0 + r) * 128 + cc * 16);
        float4* dstf = (float4*)&buf_f[r * 128 + cc * 16];
#pragma unroll
        for (int i = 0; i < 2; ++i) {
            float4 a = src[2 * i], b = src[2 * i + 1];
            dstf[2 * i]     = a;
            dstf[2 * i + 1] = b;
            int kq = cc * 2 + i;
            uint4 pk;
            pk.x = (unsigned int)f2bf(a.x) | ((unsigned int)f2bf(a.y) << 16);
            pk.y = (unsigned int)f2bf(a.z) | ((unsigned int)f2bf(a.w) << 16);
            pk.z = (unsigned int)f2bf(b.x) | ((unsigned int)f2bf(b.y) << 16);
            pk.w = (unsigned int)f2bf(b.z) | ((unsigned int)f2bf(b.w) << 16);
            *(uint4*)&xt[(r * 16 + (kq ^ (r & 7))) * 8] = pk;
        }
    }

    if constexpr (TE >= 0) {
        const int ch0 = ln * 8;      // 16 lanes x 8 ch; quads = 4 points
        float sc[8], of[8];
        {
            float4 ga = *(const float4*)(P.vgg[TE] + ch0), gb = *(const float4*)(P.vgg[TE] + ch0 + 4);
            float4 ba = *(const float4*)(P.vbt[TE] + ch0), bb = *(const float4*)(P.vbt[TE] + ch0 + 4);
            float4 ma = *(const float4*)(P.vmm[TE] + ch0), mb = *(const float4*)(P.vmm[TE] + ch0 + 4);
            float4 va = *(const float4*)(P.vva[TE] + ch0), vb = *(const float4*)(P.vva[TE] + ch0 + 4);
            const float gv[8] = {ga.x, ga.y, ga.z, ga.w, gb.x, gb.y, gb.z, gb.w};
            const float bv[8] = {ba.x, ba.y, ba.z, ba.w, bb.x, bb.y, bb.z, bb.w};
            const float mv[8] = {ma.x, ma.y, ma.z, ma.w, mb.x, mb.y, mb.z, mb.w};
            const float vvv[8] = {va.x, va.y, va.z, va.w, vb.x, vb.y, vb.z, vb.w};
#pragma unroll
            for (int j = 0; j < 8; ++j) {
                sc[j] = gv[j] * rsqrtf(vvv[j] + EPS);
                of[j] = bv[j] - mv[j] * sc[j];
            }
        }
#pragma unroll
        for (int it = 0; it < 2; ++it) {
            const int pl = it * 16 + w * 4 + q;
            const int p  = p0 + pl;
            uint4 sv = *(const uint4*)(VbIn + (size_t)p * 128 + ch0);
            const int* kp = P.knn + (size_t)p * 16;
            int4 ka = *(const int4*)(kp);
            int4 kb = *(const int4*)(kp + 4);
            int4 kc = *(const int4*)(kp + 8);
            int4 kd = *(const int4*)(kp + 12);
            const unsigned short* vbase = VbIn + ((size_t)batch << 19) + ch0;
            float m[8];
#pragma unroll
            for (int j = 0; j < 8; ++j) m[j] = -3.4e38f;
#define GATH(IDX) { uint4 u4 = *(const uint4*)(vbase + ((size_t)(IDX) << 7));      \
            m[0] = fmaxf(m[0], bf2f_lo(u4.x)); m[1] = fmaxf(m[1], bf2f_hi(u4.x)); \
            m[2] = fmaxf(m[2], bf2f_lo(u4.y)); m[3] = fmaxf(m[3], bf2f_hi(u4.y)); \
            m[4] = fmaxf(m[4], bf2f_lo(u4.z)); m[5] = fmaxf(m[5], bf2f_hi(u4.z)); \
            m[6] = fmaxf(m[6], bf2f_lo(u4.w)); m[7] = fmaxf(m[7], bf2f_hi(u4.w)); }
            GATH(ka.x) GATH(ka.y) GATH(ka.z) GATH(ka.w)
            GATH(kb.x) GATH(kb.y) GATH(kb.z) GATH(kb.w)
            GATH(kc.x) GATH(kc.y) GATH(kc.z) GATH(kc.w)
            GATH(kd.x) GATH(kd.y) GATH(kd.z) GATH(kd.w)
#undef GATH
            float s_[8];
            s_[0] = bf2f_lo(sv.x); s_[1] = bf2f_hi(sv.x);
            s_[2] = bf2f_lo(sv.y); s_[3] = bf2f_hi(sv.y);
            s_[4] = bf2f_lo(sv.z); s_[5] = bf2f_hi(sv.z);
            s_[6] = bf2f_lo(sv.w); s_[7] = bf2f_hi(sv.w);
            const float* xrow = xold_g + (size_t)p * 128 + ch0;
            float4 x0 = *(const float4*)xrow;
            float4 x1 = *(const float4*)(xrow + 4);
            float xo[8] = {x0.x, x0.y, x0.z, x0.w, x1.x, x1.y, x1.z, x1.w};
            float xn[8];
            unsigned int pw[8];
#pragma unroll
            for (int j = 0; j < 8; ++j) {
                xn[j] = xo[j] + (m[j] - s_[j]) * sc[j] + of[j];
                pw[j] = (unsigned int)f2bf(xn[j]);
            }
            *(float4*)&buf_f[pl * 128 + ch0]     = make_float4(xn[0], xn[1], xn[2], xn[3]);
            *(float4*)&buf_f[pl * 128 + ch0 + 4] = make_float4(xn[4], xn[5], xn[6], xn[7]);
            uint4 pk;
            pk.x = pw[0] | (pw[1] << 16);
            pk.y = pw[2] | (pw[3] << 16);
            pk.z = pw[4] | (pw[5] << 16);
            pk.w = pw[6] | (pw[7] << 16);
            *(uint4*)&xt[(pl * 16 + (ln ^ (pl & 7))) * 8] = pk;
        }
    }
    __syncthreads();

    // ---- residual x -> registers (epilogue layout: c=32w+16nt+ln, pt=16mt+4q+r)
    float xr[2][2][4];
#pragma unroll
    for (int mt = 0; mt < 2; ++mt)
#pragma unroll
        for (int nt = 0; nt < 2; ++nt)
#pragma unroll
            for (int r = 0; r < 4; ++r)
                xr[mt][nt][r] = buf_f[(16 * mt + 4 * q + r) * 128 + 32 * w + 16 * nt + ln];
    __syncthreads();    // buf_f now free -> h tile

    // ---------------- FFN: 4 x 128-hid slices ----------------
    floatx4 acc2[2][2];
#pragma unroll
    for (int i = 0; i < 2; ++i)
#pragma unroll
        for (int j = 0; j < 2; ++j) acc2[i][j] = zero;

    const unsigned short* W1 = P.W1P[TF];
    const unsigned short* W2 = P.W2P[TF];
    const float* b1 = P.b1s[TF];

#pragma unroll
    for (int hf = 0; hf < 4; ++hf) {
        // GEMM1: wave owns 32 hid (2 m-frags) x 32 pts (2 n-frags)
        floatx4 acc1[2][2];
#pragma unroll
        for (int i = 0; i < 2; ++i)
#pragma unroll
            for (int j = 0; j < 2; ++j) acc1[i][j] = zero;
        const unsigned short* a1 = W1 + hf * 16384 + w * 4096 + q * 128 + ln * 8;
#pragma unroll
        for (int ks = 0; ks < 4; ++ks) {
            bf16x8 bfr[2];
#pragma unroll
            for (int nt = 0; nt < 2; ++nt)
                bfr[nt] = *(const bf16x8*)&xt[((16 * nt + ln) * 16 + ((4 * ks + q) ^ sw)) * 8];
#pragma unroll
            for (int mt = 0; mt < 2; ++mt) {
                bf16x8 af = *(const bf16x8*)(a1 + mt * 2048 + ks * 512);
#pragma unroll
                for (int nt = 0; nt < 2; ++nt)
                    acc1[mt][nt] = __builtin_amdgcn_mfma_f32_16x16x32_bf16(
                        af, bfr[nt], acc1[mt][nt], 0, 0, 0);
            }
        }
        // epilogue1: +b1, relu, pack -> ht
#pragma unroll
        for (int mt = 0; mt < 2; ++mt) {
            const int hloc = 32 * w + 16 * mt + 4 * q;
            const int gh   = 128 * hf + hloc;
            const float bv0 = b1[gh], bv1 = b1[gh + 1];
            const float bv2 = b1[gh + 2], bv3 = b1[gh + 3];
            const int c16  = hloc >> 3;
            const int half = q & 1;
#pragma unroll
            for (int nt = 0; nt < 2; ++nt) {
                const int pt = 16 * nt + ln;
                float v0 = acc1[mt][nt][0] + bv0; v0 = v0 > 0.f ? v0 : 0.f;
                float v1 = acc1[mt][nt][1] + bv1; v1 = v1 > 0.f ? v1 : 0.f;
                float v2 = acc1[mt][nt][2] + bv2; v2 = v2 > 0.f ? v2 : 0.f;
                float v3 = acc1[mt][nt][3] + bv3; v3 = v3 > 0.f ? v3 : 0.f;
                uint2 pk;
                pk.x = (unsigned int)f2bf(v0) | ((unsigned int)f2bf(v1) << 16);
                pk.y = (unsigned int)f2bf(v2) | ((unsigned int)f2bf(v3) << 16);
                ht2[(pt * 16 + (c16 ^ (pt & 7))) * 2 + half] = pk;
            }
        }
        __syncthreads();
        // GEMM2: wave owns 32 ch (2 n-frags) x 32 pts (2 m-frags)
        const unsigned short* b2b = W2 + hf * 16384 + w * 4096 + q * 128 + ln * 8;
#pragma unroll
        for (int ks = 0; ks < 4; ++ks) {
            bf16x8 bw[2];
#pragma unroll
            for (int nt = 0; nt < 2; ++nt)
                bw[nt] = *(const bf16x8*)(b2b + nt * 2048 + ks * 512);
#pragma unroll
            for (int mt = 0; mt < 2; ++mt) {
                const int pt = 16 * mt + ln;
                bf16x8 ah = *(const bf16x8*)&ht2[(pt * 16 + ((4 * ks + q) ^ (pt & 7))) * 2];
#pragma unroll
                for (int nt = 0; nt < 2; ++nt)
                    acc2[mt][nt] = __builtin_amdgcn_mfma_f32_16x16x32_bf16(
                        ah, bw[nt], acc2[mt][nt], 0, 0, 0);
            }
        }
        __syncthreads();
    }

    // epilogue2: xf = xr + BN(acc2 + b2); update xt (bf16) for VFR
    {
        const float* b2   = P.b2s[TF];
        const float* gam  = P.gs[TF];
        const float* bet  = P.bes[TF];
        const float* mean = P.ms[TF];
        const float* var  = P.vvs[TF];
#pragma unroll
        for (int nt = 0; nt < 2; ++nt) {
            const int c = 32 * w + 16 * nt + ln;
            const float scv = gam[c] * rsqrtf(var[c] + EPS);
            const float off = (b2[c] - mean[c]) * scv + bet[c];
#pragma unroll
            for (int mt = 0; mt < 2; ++mt) {
#pragma unroll
                for (int r = 0; r < 4; ++r) {
                    const int pt = 16 * mt + 4 * q + r;
                    float xn = xr[mt][nt][r] + acc2[mt][nt][r] * scv + off;
                    P.xf[(size_t)(p0 + pt) * 128 + c] = xn;
                    if constexpr (TV >= 0)
                        xt[(pt * 16 + ((c >> 3) ^ (pt & 7))) * 8 + (c & 7)] = f2bf(xn);
                }
            }
        }
    }

    // ---------------- VFR linear -> VbOut (bf16) ----------------
    if constexpr (TV >= 0) {
        __syncthreads();
        const unsigned short* VT = P.VTP[TV];
        floatx4 acc[2][2];
#pragma unroll
        for (int i = 0; i < 2; ++i)
#pragma unroll
            for (int j = 0; j < 2; ++j) acc[i][j] = zero;
        const unsigned short* bb2 = VT + w * 4096 + q * 128 + ln * 8;
#pragma unroll
        for (int ks = 0; ks < 4; ++ks) {
            bf16x8 bw[2];
#pragma unroll
            for (int nt = 0; nt < 2; ++nt)
                bw[nt] = *(const bf16x8*)(bb2 + nt * 2048 + ks * 512);
#pragma unroll
            for (int mt = 0; mt < 2; ++mt) {
                bf16x8 ax = *(const bf16x8*)&xt[((16 * mt + ln) * 16 + ((4 * ks + q) ^ sw)) * 8];
#pragma unroll
                for (int nt = 0; nt < 2; ++nt)
                    acc[mt][nt] = __builtin_amdgcn_mfma_f32_16x16x32_bf16(
                        ax, bw[nt], acc[mt][nt], 0, 0, 0);
            }
        }
        const float* vb = P.vbb[TV];
#pragma unroll
        for (int nt = 0; nt < 2; ++nt) {
            const int c = 32 * w + 16 * nt + ln;
            const float bia = vb[c];
#pragma unroll
            for (int mt = 0; mt < 2; ++mt)
#pragma unroll
                for (int r = 0; r < 4; ++r) {
                    const int pt = 16 * mt + 4 * q + r;
                    VbOut[(size_t)(p0 + pt) * 128 + c] = f2bf(acc[mt][nt][r] + bia);
                }
        }
    }
}

// ---------------- launch ----------------
extern "C" void kernel_launch(void* const* d_in, const int* in_sizes, int n_in,
                              void* d_out, int out_size, void* d_ws, size_t ws_size,
                              hipStream_t stream)
{
    Params p;
    p.x_in = (const float*)d_in[0];
    p.knn  = (const int*)d_in[1];
    const float* w1  = (const float*)d_in[2];
    const float* b1  = (const float*)d_in[3];
    const float* w2  = (const float*)d_in[4];
    const float* b2  = (const float*)d_in[5];
    const float* g0  = (const float*)d_in[6];
    const float* be0 = (const float*)d_in[7];
    const float* m0p = (const float*)d_in[8];
    const float* v0p = (const float*)d_in[9];
    const float* vw  = (const float*)d_in[10];
    const float* vbp = (const float*)d_in[11];
    const float* vgp = (const float*)d_in[12];
    const float* vbe = (const float*)d_in[13];
    const float* vmp = (const float*)d_in[14];
    const float* vvp = (const float*)d_in[15];
    const float* fw1 = (const float*)d_in[16];
    const float* fb1 = (const float*)d_in[17];
    const float* fw2 = (const float*)d_in[18];
    const float* fb2 = (const float*)d_in[19];
    const float* fg  = (const float*)d_in[20];
    const float* fbe = (const float*)d_in[21];
    const float* fm  = (const float*)d_in[22];
    const float* fv  = (const float*)d_in[23];

    p.w1s[0] = w1;  p.w1s[1] = fw1; p.w1s[2] = fw1 + 65536;
    p.w2s[0] = w2;  p.w2s[1] = fw2; p.w2s[2] = fw2 + 65536;
    p.vws[0] = vw;  p.vws[1] = vw + 16384;
    p.b1s[0] = b1;  p.b1s[1] = fb1; p.b1s[2] = fb1 + 512;
    p.b2s[0] = b2;  p.b2s[1] = fb2; p.b2s[2] = fb2 + 128;
    p.gs[0]  = g0;  p.gs[1]  = fg;  p.gs[2]  = fg + 128;
    p.bes[0] = be0; p.bes[1] = fbe; p.bes[2] = fbe + 128;
    p.ms[0]  = m0p; p.ms[1]  = fm;  p.ms[2]  = fm + 128;
    p.vvs[0] = v0p; p.vvs[1] = fv;  p.vvs[2] = fv + 128;
    p.vbb[0] = vbp; p.vbb[1] = vbp + 128;
    p.vgg[0] = vgp; p.vgg[1] = vgp + 128;
    p.vbt[0] = vbe; p.vbt[1] = vbe + 128;
    p.vmm[0] = vmp; p.vmm[1] = vmp + 128;
    p.vva[0] = vvp; p.vva[1] = vvp + 128;

    char* ws = (char*)d_ws;
    unsigned short* Vb0 = (unsigned short*)ws;                          // 8 MiB
    unsigned short* Vb1 = (unsigned short*)(ws + (size_t)(8 << 20));    // 8 MiB
    unsigned short* u   = (unsigned short*)(ws + (size_t)(16 << 20));   // packed weights
    for (int i = 0; i < 3; ++i) p.W1P[i] = u + i * 65536;
    for (int i = 0; i < 3; ++i) p.W2P[i] = u + 196608 + i * 65536;
    for (int i = 0; i < 2; ++i) p.VTP[i] = u + 393216 + i * 16384;
    p.xf = (float*)d_out;

    pack_weights<<<dim3(512), 256, 0, stream>>>(p);
    stage<1, -1, 0, 0><<<dim3(1024), 256, 0, stream>>>(p, p.x_in, nullptr, Vb0);
    stage<0,  0, 1, 1><<<dim3(1024), 256, 0, stream>>>(p, p.xf, Vb0, Vb1);
    stage<0,  1, 2, -1><<<dim3(1024), 256, 0, stream>>>(p, p.xf, Vb1, nullptr);
}

// Round 10
// 187.026 us; speedup vs baseline: 1.7103x; 1.0105x over previous
//
#include <hip/hip_runtime.h>
#include <hip/hip_bf16.h>
#include <stdint.h>

typedef __attribute__((ext_vector_type(8))) __bf16 bf16x8;
typedef __attribute__((ext_vector_type(4))) float floatx4;

#define EPS 1e-5f

static __device__ __forceinline__ unsigned short f2bf(float f) {
    union { float f; unsigned int u; } x; x.f = f;
    unsigned int r = x.u + 0x7fffu + ((x.u >> 16) & 1u);
    return (unsigned short)(r >> 16);
}
static __device__ __forceinline__ float bf2f_lo(unsigned int u) {
    union { unsigned int u; float f; } x; x.u = u << 16; return x.f;
}
static __device__ __forceinline__ float bf2f_hi(unsigned int u) {
    union { unsigned int u; float f; } x; x.u = u & 0xffff0000u; return x.f;
}

struct Params {
    const float* x_in;
    const int*   knn;
    const float* w1s[3];
    const float* w2s[3];
    const float* vws[2];
    unsigned short* W1P[3];
    unsigned short* W2P[3];
    unsigned short* VTP[2];
    const float* b1s[3];
    const float* b2s[3];
    const float* gs[3];
    const float* bes[3];
    const float* ms[3];
    const float* vvs[3];
    const float* vbb[2];
    const float* vgg[2];
    const float* vbt[2];
    const float* vmm[2];
    const float* vva[2];
    float* xf;
};

// ---------------- pack weights fragment-major (bf16) for 4-wave blocks -----
// W1P: dst = hf*16384 + w*4096 + mt*2048 + ks*512 + q*128 + ln*8 + j
//      holds W1[k=32ks+8q+j][h=128hf+32w+16mt+ln]   (src [128][512])
// W2P: dst = hf*16384 + w*4096 + nt*2048 + ks*512 + q*128 + ln*8 + j
//      holds W2[h=128hf+32ks+8q+j][c=32w+16nt+ln]   (src [512][128])
// VTP: dst = w*4096 + nt*2048 + ks*512 + q*128 + ln*8 + j
//      holds Wv[k=32ks+8q+j][c=32w+16nt+ln]         (src [128][128])
__global__ __launch_bounds__(256) void pack_weights(Params P) {
    const int gtid = blockIdx.x * 256 + threadIdx.x;
    const int GT   = gridDim.x * 256;
#pragma unroll
    for (int t = 0; t < 3; ++t) {
        const float* s1 = P.w1s[t];
        unsigned short* d1 = P.W1P[t];
        for (int idx = gtid; idx < 65536; idx += GT) {
            int h = idx & 511, k = idx >> 9;
            int hf = h >> 7, w = (h >> 5) & 3, mt = (h >> 4) & 1, ln = h & 15;
            int ks = k >> 5, q = (k >> 3) & 3, j = k & 7;
            d1[hf * 16384 + w * 4096 + mt * 2048 + ks * 512 + q * 128 + ln * 8 + j]
                = f2bf(s1[idx]);
        }
        const float* s2 = P.w2s[t];
        unsigned short* d2 = P.W2P[t];
        for (int idx = gtid; idx < 65536; idx += GT) {
            int c = idx & 127, h = idx >> 7;
            int hf = h >> 7, hk = h & 127;
            int ks = hk >> 5, q = (hk >> 3) & 3, j = hk & 7;
            int w = c >> 5, nt = (c >> 4) & 1, ln = c & 15;
            d2[hf * 16384 + w * 4096 + nt * 2048 + ks * 512 + q * 128 + ln * 8 + j]
                = f2bf(s2[idx]);
        }
    }
#pragma unroll
    for (int t = 0; t < 2; ++t) {
        const float* sv = P.vws[t];
        unsigned short* dv = P.VTP[t];
        for (int idx = gtid; idx < 16384; idx += GT) {
            int c = idx & 127, k = idx >> 7;
            int ks = k >> 5, q = (k >> 3) & 3, j = k & 7;
            int w = c >> 5, nt = (c >> 4) & 1, ln = c & 15;
            dv[w * 4096 + nt * 2048 + ks * 512 + q * 128 + ln * 8 + j] = f2bf(sv[idx]);
        }
    }
}

// ---------------- fused stage (256 thr = 4 waves, 32 points/block) ---------
// LDS 24 KB: xt (bf16 x tile, 8 KB, XOR swizzle) + buf 16 KB, time-shared:
//   fp32 x staging (LOADX/edge) -> ht ping-pong (2 x 8 KB) -> Vb bf16 staging.
// Residual x in 16 fp32 VGPRs/thread. FFN: 1 barrier/slice (ping-pong), with
// GEMM2(hf) and GEMM1(hf+1) co-scheduled in the same barrier interval.
// 1024 blocks; batch = phys&7 => XCD i handles batch i (L2-local gathers).
template <int LOADX, int TE, int TF, int TV>
__global__ __launch_bounds__(256, 4)
void stage(Params P, const float* __restrict__ xold_g,
           const unsigned short* __restrict__ VbIn,
           unsigned short* __restrict__ VbOut)
{
    __shared__ __align__(16) unsigned short xt[4096];   // 8 KB
    __shared__ __align__(16) float buf_f[4096];         // 16 KB
    uint2* hta = (uint2*)buf_f;          // ping
    uint2* htb = hta + 1024;             // pong
    const int tid   = threadIdx.x;
    const int lane  = tid & 63;
    const int w     = tid >> 6;      // wave 0..3
    const int q     = lane >> 4;
    const int ln    = lane & 15;
    const int sw    = ln & 7;
    const int phys  = blockIdx.x;
    const int batch = phys & 7;
    const int blk   = phys >> 3;
    const int p0    = (batch << 12) + (blk << 5);
    const floatx4 zero = {0.f, 0.f, 0.f, 0.f};

    if constexpr (LOADX) {
        const int r = tid >> 3, cc = tid & 7;   // r 0..31, cc 0..7
        const float4* src = (const float4*)(xold_g + (size_t)(p0 + r) * 128 + cc * 16);
        float4* dstf = (float4*)&buf_f[r * 128 + cc * 16];
#pragma unroll
        for (int i = 0; i < 2; ++i) {
            float4 a = src[2 * i], b = src[2 * i + 1];
            dstf[2 * i]     = a;
            dstf[2 * i + 1] = b;
            int kq = cc * 2 + i;
            uint4 pk;
            pk.x = (unsigned int)f2bf(a.x) | ((unsigned int)f2bf(a.y) << 16);
            pk.y = (unsigned int)f2bf(a.z) | ((unsigned int)f2bf(a.w) << 16);
            pk.z = (unsigned int)f2bf(b.x) | ((unsigned int)f2bf(b.y) << 16);
            pk.w = (unsigned int)f2bf(b.z) | ((unsigned int)f2bf(b.w) << 16);
            *(uint4*)&xt[(r * 16 + (kq ^ (r & 7))) * 8] = pk;
        }
    }

    if constexpr (TE >= 0) {
        const int ch0 = ln * 8;      // 16 lanes x 8 ch; quads = 4 points
        float sc[8], of[8];
        {
            float4 ga = *(const float4*)(P.vgg[TE] + ch0), gb = *(const float4*)(P.vgg[TE] + ch0 + 4);
            float4 ba = *(const float4*)(P.vbt[TE] + ch0), bb = *(const float4*)(P.vbt[TE] + ch0 + 4);
            float4 ma = *(const float4*)(P.vmm[TE] + ch0), mb = *(const float4*)(P.vmm[TE] + ch0 + 4);
            float4 va = *(const float4*)(P.vva[TE] + ch0), vb = *(const float4*)(P.vva[TE] + ch0 + 4);
            const float gv[8] = {ga.x, ga.y, ga.z, ga.w, gb.x, gb.y, gb.z, gb.w};
            const float bv[8] = {ba.x, ba.y, ba.z, ba.w, bb.x, bb.y, bb.z, bb.w};
            const float mv[8] = {ma.x, ma.y, ma.z, ma.w, mb.x, mb.y, mb.z, mb.w};
            const float vvv[8] = {va.x, va.y, va.z, va.w, vb.x, vb.y, vb.z, vb.w};
#pragma unroll
            for (int j = 0; j < 8; ++j) {
                sc[j] = gv[j] * rsqrtf(vvv[j] + EPS);
                of[j] = bv[j] - mv[j] * sc[j];
            }
        }
#pragma unroll
        for (int it = 0; it < 2; ++it) {
            const int pl = it * 16 + w * 4 + q;
            const int p  = p0 + pl;
            uint4 sv = *(const uint4*)(VbIn + (size_t)p * 128 + ch0);
            const int* kp = P.knn + (size_t)p * 16;
            int4 ka = *(const int4*)(kp);
            int4 kb = *(const int4*)(kp + 4);
            int4 kc = *(const int4*)(kp + 8);
            int4 kd = *(const int4*)(kp + 12);
            const unsigned short* vbase = VbIn + ((size_t)batch << 19) + ch0;
            float m[8];
#pragma unroll
            for (int j = 0; j < 8; ++j) m[j] = -3.4e38f;
#define GATH(IDX) { uint4 u4 = *(const uint4*)(vbase + ((size_t)(IDX) << 7));      \
            m[0] = fmaxf(m[0], bf2f_lo(u4.x)); m[1] = fmaxf(m[1], bf2f_hi(u4.x)); \
            m[2] = fmaxf(m[2], bf2f_lo(u4.y)); m[3] = fmaxf(m[3], bf2f_hi(u4.y)); \
            m[4] = fmaxf(m[4], bf2f_lo(u4.z)); m[5] = fmaxf(m[5], bf2f_hi(u4.z)); \
            m[6] = fmaxf(m[6], bf2f_lo(u4.w)); m[7] = fmaxf(m[7], bf2f_hi(u4.w)); }
            GATH(ka.x) GATH(ka.y) GATH(ka.z) GATH(ka.w)
            GATH(kb.x) GATH(kb.y) GATH(kb.z) GATH(kb.w)
            GATH(kc.x) GATH(kc.y) GATH(kc.z) GATH(kc.w)
            GATH(kd.x) GATH(kd.y) GATH(kd.z) GATH(kd.w)
#undef GATH
            float s_[8];
            s_[0] = bf2f_lo(sv.x); s_[1] = bf2f_hi(sv.x);
            s_[2] = bf2f_lo(sv.y); s_[3] = bf2f_hi(sv.y);
            s_[4] = bf2f_lo(sv.z); s_[5] = bf2f_hi(sv.z);
            s_[6] = bf2f_lo(sv.w); s_[7] = bf2f_hi(sv.w);
            const float* xrow = xold_g + (size_t)p * 128 + ch0;
            float4 x0 = *(const float4*)xrow;
            float4 x1 = *(const float4*)(xrow + 4);
            float xo[8] = {x0.x, x0.y, x0.z, x0.w, x1.x, x1.y, x1.z, x1.w};
            float xn[8];
            unsigned int pw[8];
#pragma unroll
            for (int j = 0; j < 8; ++j) {
                xn[j] = xo[j] + (m[j] - s_[j]) * sc[j] + of[j];
                pw[j] = (unsigned int)f2bf(xn[j]);
            }
            *(float4*)&buf_f[pl * 128 + ch0]     = make_float4(xn[0], xn[1], xn[2], xn[3]);
            *(float4*)&buf_f[pl * 128 + ch0 + 4] = make_float4(xn[4], xn[5], xn[6], xn[7]);
            uint4 pk;
            pk.x = pw[0] | (pw[1] << 16);
            pk.y = pw[2] | (pw[3] << 16);
            pk.z = pw[4] | (pw[5] << 16);
            pk.w = pw[6] | (pw[7] << 16);
            *(uint4*)&xt[(pl * 16 + (ln ^ (pl & 7))) * 8] = pk;
        }
    }
    __syncthreads();                                        // A: xt/buf ready

    // ---- residual x -> registers (epilogue layout: c=32w+16nt+ln, pt=16mt+4q+r)
    float xr[2][2][4];
#pragma unroll
    for (int mt = 0; mt < 2; ++mt)
#pragma unroll
        for (int nt = 0; nt < 2; ++nt)
#pragma unroll
            for (int r = 0; r < 4; ++r)
                xr[mt][nt][r] = buf_f[(16 * mt + 4 * q + r) * 128 + 32 * w + 16 * nt + ln];
    __syncthreads();                                        // B: buf -> ht

    // ---------------- FFN: 4 x 128-hid slices, ht ping-pong ----------------
    floatx4 acc2[2][2];
#pragma unroll
    for (int i = 0; i < 2; ++i)
#pragma unroll
        for (int j = 0; j < 2; ++j) acc2[i][j] = zero;

    const unsigned short* W1 = P.W1P[TF];
    const unsigned short* W2 = P.W2P[TF];
    const float* b1 = P.b1s[TF];

    // GEMM1 of slice hf -> dst (+b1, relu, bf16 pack)
    auto g1 = [&](int hf, uint2* dst) {
        floatx4 acc1[2][2];
#pragma unroll
        for (int i = 0; i < 2; ++i)
#pragma unroll
            for (int j = 0; j < 2; ++j) acc1[i][j] = zero;
        const unsigned short* a1 = W1 + hf * 16384 + w * 4096 + q * 128 + ln * 8;
#pragma unroll
        for (int ks = 0; ks < 4; ++ks) {
            bf16x8 bfr[2];
#pragma unroll
            for (int nt = 0; nt < 2; ++nt)
                bfr[nt] = *(const bf16x8*)&xt[((16 * nt + ln) * 16 + ((4 * ks + q) ^ sw)) * 8];
#pragma unroll
            for (int mt = 0; mt < 2; ++mt) {
                bf16x8 af = *(const bf16x8*)(a1 + mt * 2048 + ks * 512);
#pragma unroll
                for (int nt = 0; nt < 2; ++nt)
                    acc1[mt][nt] = __builtin_amdgcn_mfma_f32_16x16x32_bf16(
                        af, bfr[nt], acc1[mt][nt], 0, 0, 0);
            }
        }
#pragma unroll
        for (int mt = 0; mt < 2; ++mt) {
            const int hloc = 32 * w + 16 * mt + 4 * q;
            const int gh   = 128 * hf + hloc;
            const float bv0 = b1[gh], bv1 = b1[gh + 1];
            const float bv2 = b1[gh + 2], bv3 = b1[gh + 3];
            const int c16  = hloc >> 3;
            const int half = q & 1;
#pragma unroll
            for (int nt = 0; nt < 2; ++nt) {
                const int pt = 16 * nt + ln;
                float v0 = acc1[mt][nt][0] + bv0; v0 = v0 > 0.f ? v0 : 0.f;
                float v1 = acc1[mt][nt][1] + bv1; v1 = v1 > 0.f ? v1 : 0.f;
                float v2 = acc1[mt][nt][2] + bv2; v2 = v2 > 0.f ? v2 : 0.f;
                float v3 = acc1[mt][nt][3] + bv3; v3 = v3 > 0.f ? v3 : 0.f;
                uint2 pk;
                pk.x = (unsigned int)f2bf(v0) | ((unsigned int)f2bf(v1) << 16);
                pk.y = (unsigned int)f2bf(v2) | ((unsigned int)f2bf(v3) << 16);
                dst[(pt * 16 + (c16 ^ (pt & 7))) * 2 + half] = pk;
            }
        }
    };

    g1(0, hta);
    __syncthreads();                                        // C
#pragma unroll
    for (int hf = 0; hf < 4; ++hf) {
        uint2* cur = (hf & 1) ? htb : hta;
        // GEMM2(hf): reads cur; co-scheduled with GEMM1(hf+1) writing the other
        const unsigned short* b2b = W2 + hf * 16384 + w * 4096 + q * 128 + ln * 8;
#pragma unroll
        for (int ks = 0; ks < 4; ++ks) {
            bf16x8 bw[2];
#pragma unroll
            for (int nt = 0; nt < 2; ++nt)
                bw[nt] = *(const bf16x8*)(b2b + nt * 2048 + ks * 512);
#pragma unroll
            for (int mt = 0; mt < 2; ++mt) {
                const int pt = 16 * mt + ln;
                bf16x8 ah = *(const bf16x8*)&cur[(pt * 16 + ((4 * ks + q) ^ (pt & 7))) * 2];
#pragma unroll
                for (int nt = 0; nt < 2; ++nt)
                    acc2[mt][nt] = __builtin_amdgcn_mfma_f32_16x16x32_bf16(
                        ah, bw[nt], acc2[mt][nt], 0, 0, 0);
            }
        }
        if (hf < 3) g1(hf + 1, (hf & 1) ? hta : htb);
        __syncthreads();                                    // D..G
    }

    // epilogue2: xf = xr + BN(acc2 + b2); update xt (bf16) for VFR
    {
        const float* b2   = P.b2s[TF];
        const float* gam  = P.gs[TF];
        const float* bet  = P.bes[TF];
        const float* mean = P.ms[TF];
        const float* var  = P.vvs[TF];
#pragma unroll
        for (int nt = 0; nt < 2; ++nt) {
            const int c = 32 * w + 16 * nt + ln;
            const float scv = gam[c] * rsqrtf(var[c] + EPS);
            const float off = (b2[c] - mean[c]) * scv + bet[c];
#pragma unroll
            for (int mt = 0; mt < 2; ++mt) {
#pragma unroll
                for (int r = 0; r < 4; ++r) {
                    const int pt = 16 * mt + 4 * q + r;
                    float xn = xr[mt][nt][r] + acc2[mt][nt][r] * scv + off;
                    P.xf[(size_t)(p0 + pt) * 128 + c] = xn;
                    if constexpr (TV >= 0)
                        xt[(pt * 16 + ((c >> 3) ^ (pt & 7))) * 8 + (c & 7)] = f2bf(xn);
                }
            }
        }
    }

    // ---------------- VFR linear -> buf (bf16) -> coalesced VbOut ----------
    if constexpr (TV >= 0) {
        __syncthreads();                                    // H: xt ready, buf free
        const unsigned short* VT = P.VTP[TV];
        floatx4 acc[2][2];
#pragma unroll
        for (int i = 0; i < 2; ++i)
#pragma unroll
            for (int j = 0; j < 2; ++j) acc[i][j] = zero;
        const unsigned short* bb2 = VT + w * 4096 + q * 128 + ln * 8;
#pragma unroll
        for (int ks = 0; ks < 4; ++ks) {
            bf16x8 bw[2];
#pragma unroll
            for (int nt = 0; nt < 2; ++nt)
                bw[nt] = *(const bf16x8*)(bb2 + nt * 2048 + ks * 512);
#pragma unroll
            for (int mt = 0; mt < 2; ++mt) {
                bf16x8 ax = *(const bf16x8*)&xt[((16 * mt + ln) * 16 + ((4 * ks + q) ^ sw)) * 8];
#pragma unroll
                for (int nt = 0; nt < 2; ++nt)
                    acc[mt][nt] = __builtin_amdgcn_mfma_f32_16x16x32_bf16(
                        ax, bw[nt], acc[mt][nt], 0, 0, 0);
            }
        }
        const float* vb = P.vbb[TV];
        unsigned short* vstage = (unsigned short*)buf_f;    // 8 KB staging
#pragma unroll
        for (int nt = 0; nt < 2; ++nt) {
            const int c = 32 * w + 16 * nt + ln;
            const float bia = vb[c];
#pragma unroll
            for (int mt = 0; mt < 2; ++mt)
#pragma unroll
                for (int r = 0; r < 4; ++r) {
                    const int pt = 16 * mt + 4 * q + r;
                    vstage[pt * 128 + c] = f2bf(acc[mt][nt][r] + bia);
                }
        }
        __syncthreads();                                    // I
        const int rr = tid >> 3, seg = tid & 7;
        const uint4* srcv = (const uint4*)&vstage[rr * 128 + seg * 16];
        uint4 a = srcv[0], b = srcv[1];
        uint4* dstv = (uint4*)(VbOut + (size_t)(p0 + rr) * 128 + seg * 16);
        dstv[0] = a; dstv[1] = b;
    }
}

// ---------------- launch ----------------
extern "C" void kernel_launch(void* const* d_in, const int* in_sizes, int n_in,
                              void* d_out, int out_size, void* d_ws, size_t ws_size,
                              hipStream_t stream)
{
    Params p;
    p.x_in = (const float*)d_in[0];
    p.knn  = (const int*)d_in[1];
    const float* w1  = (const float*)d_in[2];
    const float* b1  = (const float*)d_in[3];
    const float* w2  = (const float*)d_in[4];
    const float* b2  = (const float*)d_in[5];
    const float* g0  = (const float*)d_in[6];
    const float* be0 = (const float*)d_in[7];
    const float* m0p = (const float*)d_in[8];
    const float* v0p = (const float*)d_in[9];
    const float* vw  = (const float*)d_in[10];
    const float* vbp = (const float*)d_in[11];
    const float* vgp = (const float*)d_in[12];
    const float* vbe = (const float*)d_in[13];
    const float* vmp = (const float*)d_in[14];
    const float* vvp = (const float*)d_in[15];
    const float* fw1 = (const float*)d_in[16];
    const float* fb1 = (const float*)d_in[17];
    const float* fw2 = (const float*)d_in[18];
    const float* fb2 = (const float*)d_in[19];
    const float* fg  = (const float*)d_in[20];
    const float* fbe = (const float*)d_in[21];
    const float* fm  = (const float*)d_in[22];
    const float* fv  = (const float*)d_in[23];

    p.w1s[0] = w1;  p.w1s[1] = fw1; p.w1s[2] = fw1 + 65536;
    p.w2s[0] = w2;  p.w2s[1] = fw2; p.w2s[2] = fw2 + 65536;
    p.vws[0] = vw;  p.vws[1] = vw + 16384;
    p.b1s[0] = b1;  p.b1s[1] = fb1; p.b1s[2] = fb1 + 512;
    p.b2s[0] = b2;  p.b2s[1] = fb2; p.b2s[2] = fb2 + 128;
    p.gs[0]  = g0;  p.gs[1]  = fg;  p.gs[2]  = fg + 128;
    p.bes[0] = be0; p.bes[1] = fbe; p.bes[2] = fbe + 128;
    p.ms[0]  = m0p; p.ms[1]  = fm;  p.ms[2]  = fm + 128;
    p.vvs[0] = v0p; p.vvs[1] = fv;  p.vvs[2] = fv + 128;
    p.vbb[0] = vbp; p.vbb[1] = vbp + 128;
    p.vgg[0] = vgp; p.vgg[1] = vgp + 128;
    p.vbt[0] = vbe; p.vbt[1] = vbe + 128;
    p.vmm[0] = vmp; p.vmm[1] = vmp + 128;
    p.vva[0] = vvp; p.vva[1] = vvp + 128;

    char* ws = (char*)d_ws;
    unsigned short* Vb0 = (unsigned short*)ws;                          // 8 MiB
    unsigned short* Vb1 = (unsigned short*)(ws + (size_t)(8 << 20));    // 8 MiB
    unsigned short* u   = (unsigned short*)(ws + (size_t)(16 << 20));   // packed weights
    for (int i = 0; i < 3; ++i) p.W1P[i] = u + i * 65536;
    for (int i = 0; i < 3; ++i) p.W2P[i] = u + 196608 + i * 65536;
    for (int i = 0; i < 2; ++i) p.VTP[i] = u + 393216 + i * 16384;
    p.xf = (float*)d_out;

    pack_weights<<<dim3(512), 256, 0, stream>>>(p);
    stage<1, -1, 0, 0><<<dim3(1024), 256, 0, stream>>>(p, p.x_in, nullptr, Vb0);
    stage<0,  0, 1, 1><<<dim3(1024), 256, 0, stream>>>(p, p.xf, Vb0, Vb1);
    stage<0,  1, 2, -1><<<dim3(1024), 256, 0, stream>>>(p, p.xf, Vb1, nullptr);
}

// Round 11
// 186.201 us; speedup vs baseline: 1.7179x; 1.0044x over previous
//
#include <hip/hip_runtime.h>
#include <hip/hip_bf16.h>
#include <stdint.h>

typedef __attribute__((ext_vector_type(8))) __bf16 bf16x8;
typedef __attribute__((ext_vector_type(4))) float floatx4;

#define EPS 1e-5f

static __device__ __forceinline__ unsigned short f2bf(float f) {
    union { float f; unsigned int u; } x; x.f = f;
    unsigned int r = x.u + 0x7fffu + ((x.u >> 16) & 1u);
    return (unsigned short)(r >> 16);
}
static __device__ __forceinline__ float bf2f_lo(unsigned int u) {
    union { unsigned int u; float f; } x; x.u = u << 16; return x.f;
}
static __device__ __forceinline__ float bf2f_hi(unsigned int u) {
    union { unsigned int u; float f; } x; x.u = u & 0xffff0000u; return x.f;
}

struct Params {
    const float* x_in;
    const int*   knn;
    const float* w1s[3];
    const float* w2s[3];
    const float* vws[2];
    unsigned short* W1P[3];
    unsigned short* W2P[3];
    unsigned short* VTP[2];
    const float* b1s[3];
    const float* b2s[3];
    const float* gs[3];
    const float* bes[3];
    const float* ms[3];
    const float* vvs[3];
    const float* vbb[2];
    const float* vgg[2];
    const float* vbt[2];
    const float* vmm[2];
    const float* vva[2];
    unsigned short* xb;    // bf16 x carried between stages
    float* xf;             // fp32 final output (d_out)
};

// ---------------- pack weights: DST-major iteration (coalesced writes) -----
// Layouts identical to r10; reads are scattered 4B from L2-hot weights,
// writes are fully coalesced bf16.
__global__ __launch_bounds__(256) void pack_weights(Params P) {
    const int gtid = blockIdx.x * 256 + threadIdx.x;
    const int GT   = gridDim.x * 256;
#pragma unroll
    for (int t = 0; t < 3; ++t) {
        const float* s1 = P.w1s[t];
        unsigned short* d1 = P.W1P[t];
        for (int d = gtid; d < 65536; d += GT) {
            int j = d & 7, ln = (d >> 3) & 15, q = (d >> 7) & 3, ks = (d >> 9) & 3;
            int mt = (d >> 11) & 1, w = (d >> 12) & 3, hf = (d >> 14) & 3;
            int k = 32 * ks + 8 * q + j;
            int h = 128 * hf + 32 * w + 16 * mt + ln;
            d1[d] = f2bf(s1[k * 512 + h]);
        }
        const float* s2 = P.w2s[t];
        unsigned short* d2 = P.W2P[t];
        for (int d = gtid; d < 65536; d += GT) {
            int j = d & 7, ln = (d >> 3) & 15, q = (d >> 7) & 3, ks = (d >> 9) & 3;
            int nt = (d >> 11) & 1, w = (d >> 12) & 3, hf = (d >> 14) & 3;
            int h = 128 * hf + 32 * ks + 8 * q + j;
            int c = 32 * w + 16 * nt + ln;
            d2[d] = f2bf(s2[h * 128 + c]);
        }
    }
#pragma unroll
    for (int t = 0; t < 2; ++t) {
        const float* sv = P.vws[t];
        unsigned short* dv = P.VTP[t];
        for (int d = gtid; d < 16384; d += GT) {
            int j = d & 7, ln = (d >> 3) & 15, q = (d >> 7) & 3, ks = (d >> 9) & 3;
            int nt = (d >> 11) & 1, w = (d >> 12) & 3;
            int k = 32 * ks + 8 * q + j;
            int c = 32 * w + 16 * nt + ln;
            dv[d] = f2bf(sv[k * 128 + c]);
        }
    }
}

// ---------------- fused stage (256 thr = 4 waves, 32 points/block) ---------
// LDS 24 KB: xt (bf16 x tile, 8 KB, XOR swizzle) + buf 16 KB, time-shared:
//   fp32 x staging (LOADX/edge) -> ht ping-pong (2 x 8 KB) -> Vb bf16 staging.
// Residual x in 16 fp32 VGPRs/thread. x crosses stage boundaries as bf16
// (P.xb); fp32 d_out written only by the LAST stage.
// 1024 blocks; batch = phys&7 => XCD i handles batch i (L2-local gathers).
template <int LOADX, int TE, int TF, int TV, int LAST>
__global__ __launch_bounds__(256, 4)
void stage(Params P,
           const unsigned short* __restrict__ VbIn,
           unsigned short* __restrict__ VbOut)
{
    __shared__ __align__(16) unsigned short xt[4096];   // 8 KB
    __shared__ __align__(16) float buf_f[4096];         // 16 KB
    uint2* hta = (uint2*)buf_f;          // ping
    uint2* htb = hta + 1024;             // pong
    const int tid   = threadIdx.x;
    const int lane  = tid & 63;
    const int w     = tid >> 6;      // wave 0..3
    const int q     = lane >> 4;
    const int ln    = lane & 15;
    const int sw    = ln & 7;
    const int phys  = blockIdx.x;
    const int batch = phys & 7;
    const int blk   = phys >> 3;
    const int p0    = (batch << 12) + (blk << 5);
    const floatx4 zero = {0.f, 0.f, 0.f, 0.f};

    if constexpr (LOADX) {
        const int r = tid >> 3, cc = tid & 7;   // r 0..31, cc 0..7
        const float4* src = (const float4*)(P.x_in + (size_t)(p0 + r) * 128 + cc * 16);
        float4* dstf = (float4*)&buf_f[r * 128 + cc * 16];
#pragma unroll
        for (int i = 0; i < 2; ++i) {
            float4 a = src[2 * i], b = src[2 * i + 1];
            dstf[2 * i]     = a;
            dstf[2 * i + 1] = b;
            int kq = cc * 2 + i;
            uint4 pk;
            pk.x = (unsigned int)f2bf(a.x) | ((unsigned int)f2bf(a.y) << 16);
            pk.y = (unsigned int)f2bf(a.z) | ((unsigned int)f2bf(a.w) << 16);
            pk.z = (unsigned int)f2bf(b.x) | ((unsigned int)f2bf(b.y) << 16);
            pk.w = (unsigned int)f2bf(b.z) | ((unsigned int)f2bf(b.w) << 16);
            *(uint4*)&xt[(r * 16 + (kq ^ (r & 7))) * 8] = pk;
        }
    }

    if constexpr (TE >= 0) {
        const int ch0 = ln * 8;      // 16 lanes x 8 ch; quads = 4 points
        float sc[8], of[8];
        {
            float4 ga = *(const float4*)(P.vgg[TE] + ch0), gb = *(const float4*)(P.vgg[TE] + ch0 + 4);
            float4 ba = *(const float4*)(P.vbt[TE] + ch0), bb = *(const float4*)(P.vbt[TE] + ch0 + 4);
            float4 ma = *(const float4*)(P.vmm[TE] + ch0), mb = *(const float4*)(P.vmm[TE] + ch0 + 4);
            float4 va = *(const float4*)(P.vva[TE] + ch0), vb = *(const float4*)(P.vva[TE] + ch0 + 4);
            const float gv[8] = {ga.x, ga.y, ga.z, ga.w, gb.x, gb.y, gb.z, gb.w};
            const float bv[8] = {ba.x, ba.y, ba.z, ba.w, bb.x, bb.y, bb.z, bb.w};
            const float mv[8] = {ma.x, ma.y, ma.z, ma.w, mb.x, mb.y, mb.z, mb.w};
            const float vvv[8] = {va.x, va.y, va.z, va.w, vb.x, vb.y, vb.z, vb.w};
#pragma unroll
            for (int j = 0; j < 8; ++j) {
                sc[j] = gv[j] * rsqrtf(vvv[j] + EPS);
                of[j] = bv[j] - mv[j] * sc[j];
            }
        }
#pragma unroll
        for (int it = 0; it < 2; ++it) {
            const int pl = it * 16 + w * 4 + q;
            const int p  = p0 + pl;
            uint4 sv = *(const uint4*)(VbIn + (size_t)p * 128 + ch0);
            const int* kp = P.knn + (size_t)p * 16;
            int4 ka = *(const int4*)(kp);
            int4 kb = *(const int4*)(kp + 4);
            int4 kc = *(const int4*)(kp + 8);
            int4 kd = *(const int4*)(kp + 12);
            const unsigned short* vbase = VbIn + ((size_t)batch << 19) + ch0;
            float m[8];
#pragma unroll
            for (int j = 0; j < 8; ++j) m[j] = -3.4e38f;
#define GATH(IDX) { uint4 u4 = *(const uint4*)(vbase + ((size_t)(IDX) << 7));      \
            m[0] = fmaxf(m[0], bf2f_lo(u4.x)); m[1] = fmaxf(m[1], bf2f_hi(u4.x)); \
            m[2] = fmaxf(m[2], bf2f_lo(u4.y)); m[3] = fmaxf(m[3], bf2f_hi(u4.y)); \
            m[4] = fmaxf(m[4], bf2f_lo(u4.z)); m[5] = fmaxf(m[5], bf2f_hi(u4.z)); \
            m[6] = fmaxf(m[6], bf2f_lo(u4.w)); m[7] = fmaxf(m[7], bf2f_hi(u4.w)); }
            GATH(ka.x) GATH(ka.y) GATH(ka.z) GATH(ka.w)
            GATH(kb.x) GATH(kb.y) GATH(kb.z) GATH(kb.w)
            GATH(kc.x) GATH(kc.y) GATH(kc.z) GATH(kc.w)
            GATH(kd.x) GATH(kd.y) GATH(kd.z) GATH(kd.w)
#undef GATH
            float s_[8];
            s_[0] = bf2f_lo(sv.x); s_[1] = bf2f_hi(sv.x);
            s_[2] = bf2f_lo(sv.y); s_[3] = bf2f_hi(sv.y);
            s_[4] = bf2f_lo(sv.z); s_[5] = bf2f_hi(sv.z);
            s_[6] = bf2f_lo(sv.w); s_[7] = bf2f_hi(sv.w);
            // base x from bf16 inter-stage buffer
            uint4 xv = *(const uint4*)(P.xb + (size_t)p * 128 + ch0);
            float xo[8];
            xo[0] = bf2f_lo(xv.x); xo[1] = bf2f_hi(xv.x);
            xo[2] = bf2f_lo(xv.y); xo[3] = bf2f_hi(xv.y);
            xo[4] = bf2f_lo(xv.z); xo[5] = bf2f_hi(xv.z);
            xo[6] = bf2f_lo(xv.w); xo[7] = bf2f_hi(xv.w);
            float xn[8];
            unsigned int pw[8];
#pragma unroll
            for (int j = 0; j < 8; ++j) {
                xn[j] = xo[j] + (m[j] - s_[j]) * sc[j] + of[j];
                pw[j] = (unsigned int)f2bf(xn[j]);
            }
            *(float4*)&buf_f[pl * 128 + ch0]     = make_float4(xn[0], xn[1], xn[2], xn[3]);
            *(float4*)&buf_f[pl * 128 + ch0 + 4] = make_float4(xn[4], xn[5], xn[6], xn[7]);
            uint4 pk;
            pk.x = pw[0] | (pw[1] << 16);
            pk.y = pw[2] | (pw[3] << 16);
            pk.z = pw[4] | (pw[5] << 16);
            pk.w = pw[6] | (pw[7] << 16);
            *(uint4*)&xt[(pl * 16 + (ln ^ (pl & 7))) * 8] = pk;
        }
    }
    __syncthreads();                                        // A: xt/buf ready

    // ---- residual x -> registers (epilogue layout: c=32w+16nt+ln, pt=16mt+4q+r)
    float xr[2][2][4];
#pragma unroll
    for (int mt = 0; mt < 2; ++mt)
#pragma unroll
        for (int nt = 0; nt < 2; ++nt)
#pragma unroll
            for (int r = 0; r < 4; ++r)
                xr[mt][nt][r] = buf_f[(16 * mt + 4 * q + r) * 128 + 32 * w + 16 * nt + ln];
    __syncthreads();                                        // B: buf -> ht

    // ---------------- FFN: 4 x 128-hid slices, ht ping-pong ----------------
    floatx4 acc2[2][2];
#pragma unroll
    for (int i = 0; i < 2; ++i)
#pragma unroll
        for (int j = 0; j < 2; ++j) acc2[i][j] = zero;

    const unsigned short* W1 = P.W1P[TF];
    const unsigned short* W2 = P.W2P[TF];
    const float* b1 = P.b1s[TF];

    auto g1 = [&](int hf, uint2* dst) {
        floatx4 acc1[2][2];
#pragma unroll
        for (int i = 0; i < 2; ++i)
#pragma unroll
            for (int j = 0; j < 2; ++j) acc1[i][j] = zero;
        const unsigned short* a1 = W1 + hf * 16384 + w * 4096 + q * 128 + ln * 8;
#pragma unroll
        for (int ks = 0; ks < 4; ++ks) {
            bf16x8 bfr[2];
#pragma unroll
            for (int nt = 0; nt < 2; ++nt)
                bfr[nt] = *(const bf16x8*)&xt[((16 * nt + ln) * 16 + ((4 * ks + q) ^ sw)) * 8];
#pragma unroll
            for (int mt = 0; mt < 2; ++mt) {
                bf16x8 af = *(const bf16x8*)(a1 + mt * 2048 + ks * 512);
#pragma unroll
                for (int nt = 0; nt < 2; ++nt)
                    acc1[mt][nt] = __builtin_amdgcn_mfma_f32_16x16x32_bf16(
                        af, bfr[nt], acc1[mt][nt], 0, 0, 0);
            }
        }
#pragma unroll
        for (int mt = 0; mt < 2; ++mt) {
            const int hloc = 32 * w + 16 * mt + 4 * q;
            const int gh   = 128 * hf + hloc;
            const float bv0 = b1[gh], bv1 = b1[gh + 1];
            const float bv2 = b1[gh + 2], bv3 = b1[gh + 3];
            const int c16  = hloc >> 3;
            const int half = q & 1;
#pragma unroll
            for (int nt = 0; nt < 2; ++nt) {
                const int pt = 16 * nt + ln;
                float v0 = acc1[mt][nt][0] + bv0; v0 = v0 > 0.f ? v0 : 0.f;
                float v1 = acc1[mt][nt][1] + bv1; v1 = v1 > 0.f ? v1 : 0.f;
                float v2 = acc1[mt][nt][2] + bv2; v2 = v2 > 0.f ? v2 : 0.f;
                float v3 = acc1[mt][nt][3] + bv3; v3 = v3 > 0.f ? v3 : 0.f;
                uint2 pk;
                pk.x = (unsigned int)f2bf(v0) | ((unsigned int)f2bf(v1) << 16);
                pk.y = (unsigned int)f2bf(v2) | ((unsigned int)f2bf(v3) << 16);
                dst[(pt * 16 + (c16 ^ (pt & 7))) * 2 + half] = pk;
            }
        }
    };

    g1(0, hta);
    __syncthreads();                                        // C
#pragma unroll
    for (int hf = 0; hf < 4; ++hf) {
        uint2* cur = (hf & 1) ? htb : hta;
        const unsigned short* b2b = W2 + hf * 16384 + w * 4096 + q * 128 + ln * 8;
#pragma unroll
        for (int ks = 0; ks < 4; ++ks) {
            bf16x8 bw[2];
#pragma unroll
            for (int nt = 0; nt < 2; ++nt)
                bw[nt] = *(const bf16x8*)(b2b + nt * 2048 + ks * 512);
#pragma unroll
            for (int mt = 0; mt < 2; ++mt) {
                const int pt = 16 * mt + ln;
                bf16x8 ah = *(const bf16x8*)&cur[(pt * 16 + ((4 * ks + q) ^ (pt & 7))) * 2];
#pragma unroll
                for (int nt = 0; nt < 2; ++nt)
                    acc2[mt][nt] = __builtin_amdgcn_mfma_f32_16x16x32_bf16(
                        ah, bw[nt], acc2[mt][nt], 0, 0, 0);
            }
        }
        if (hf < 3) g1(hf + 1, (hf & 1) ? hta : htb);
        __syncthreads();                                    // D..G
    }

    // epilogue2: x = xr + BN(acc2 + b2); LAST -> fp32 d_out, else bf16 xb (+xt)
    {
        const float* b2   = P.b2s[TF];
        const float* gam  = P.gs[TF];
        const float* bet  = P.bes[TF];
        const float* mean = P.ms[TF];
        const float* var  = P.vvs[TF];
#pragma unroll
        for (int nt = 0; nt < 2; ++nt) {
            const int c = 32 * w + 16 * nt + ln;
            const float scv = gam[c] * rsqrtf(var[c] + EPS);
            const float off = (b2[c] - mean[c]) * scv + bet[c];
#pragma unroll
            for (int mt = 0; mt < 2; ++mt) {
#pragma unroll
                for (int r = 0; r < 4; ++r) {
                    const int pt = 16 * mt + 4 * q + r;
                    float xn = xr[mt][nt][r] + acc2[mt][nt][r] * scv + off;
                    if constexpr (LAST) {
                        P.xf[(size_t)(p0 + pt) * 128 + c] = xn;
                    } else {
                        unsigned short xb16 = f2bf(xn);
                        P.xb[(size_t)(p0 + pt) * 128 + c] = xb16;
                        if constexpr (TV >= 0)
                            xt[(pt * 16 + ((c >> 3) ^ (pt & 7))) * 8 + (c & 7)] = xb16;
                    }
                }
            }
        }
    }

    // ---------------- VFR linear -> buf (bf16) -> coalesced VbOut ----------
    if constexpr (TV >= 0) {
        __syncthreads();                                    // H: xt ready, buf free
        const unsigned short* VT = P.VTP[TV];
        floatx4 acc[2][2];
#pragma unroll
        for (int i = 0; i < 2; ++i)
#pragma unroll
            for (int j = 0; j < 2; ++j) acc[i][j] = zero;
        const unsigned short* bb2 = VT + w * 4096 + q * 128 + ln * 8;
#pragma unroll
        for (int ks = 0; ks < 4; ++ks) {
            bf16x8 bw[2];
#pragma unroll
            for (int nt = 0; nt < 2; ++nt)
                bw[nt] = *(const bf16x8*)(bb2 + nt * 2048 + ks * 512);
#pragma unroll
            for (int mt = 0; mt < 2; ++mt) {
                bf16x8 ax = *(const bf16x8*)&xt[((16 * mt + ln) * 16 + ((4 * ks + q) ^ sw)) * 8];
#pragma unroll
                for (int nt = 0; nt < 2; ++nt)
                    acc[mt][nt] = __builtin_amdgcn_mfma_f32_16x16x32_bf16(
                        ax, bw[nt], acc[mt][nt], 0, 0, 0);
            }
        }
        const float* vb = P.vbb[TV];
        unsigned short* vstage = (unsigned short*)buf_f;    // 8 KB staging
#pragma unroll
        for (int nt = 0; nt < 2; ++nt) {
            const int c = 32 * w + 16 * nt + ln;
            const float bia = vb[c];
#pragma unroll
            for (int mt = 0; mt < 2; ++mt)
#pragma unroll
                for (int r = 0; r < 4; ++r) {
                    const int pt = 16 * mt + 4 * q + r;
                    vstage[pt * 128 + c] = f2bf(acc[mt][nt][r] + bia);
                }
        }
        __syncthreads();                                    // I
        const int rr = tid >> 3, seg = tid & 7;
        const uint4* srcv = (const uint4*)&vstage[rr * 128 + seg * 16];
        uint4 a = srcv[0], b = srcv[1];
        uint4* dstv = (uint4*)(VbOut + (size_t)(p0 + rr) * 128 + seg * 16);
        dstv[0] = a; dstv[1] = b;
    }
}

// ---------------- launch ----------------
extern "C" void kernel_launch(void* const* d_in, const int* in_sizes, int n_in,
                              void* d_out, int out_size, void* d_ws, size_t ws_size,
                              hipStream_t stream)
{
    Params p;
    p.x_in = (const float*)d_in[0];
    p.knn  = (const int*)d_in[1];
    const float* w1  = (const float*)d_in[2];
    const float* b1  = (const float*)d_in[3];
    const float* w2  = (const float*)d_in[4];
    const float* b2  = (const float*)d_in[5];
    const float* g0  = (const float*)d_in[6];
    const float* be0 = (const float*)d_in[7];
    const float* m0p = (const float*)d_in[8];
    const float* v0p = (const float*)d_in[9];
    const float* vw  = (const float*)d_in[10];
    const float* vbp = (const float*)d_in[11];
    const float* vgp = (const float*)d_in[12];
    const float* vbe = (const float*)d_in[13];
    const float* vmp = (const float*)d_in[14];
    const float* vvp = (const float*)d_in[15];
    const float* fw1 = (const float*)d_in[16];
    const float* fb1 = (const float*)d_in[17];
    const float* fw2 = (const float*)d_in[18];
    const float* fb2 = (const float*)d_in[19];
    const float* fg  = (const float*)d_in[20];
    const float* fbe = (const float*)d_in[21];
    const float* fm  = (const float*)d_in[22];
    const float* fv  = (const float*)d_in[23];

    p.w1s[0] = w1;  p.w1s[1] = fw1; p.w1s[2] = fw1 + 65536;
    p.w2s[0] = w2;  p.w2s[1] = fw2; p.w2s[2] = fw2 + 65536;
    p.vws[0] = vw;  p.vws[1] = vw + 16384;
    p.b1s[0] = b1;  p.b1s[1] = fb1; p.b1s[2] = fb1 + 512;
    p.b2s[0] = b2;  p.b2s[1] = fb2; p.b2s[2] = fb2 + 128;
    p.gs[0]  = g0;  p.gs[1]  = fg;  p.gs[2]  = fg + 128;
    p.bes[0] = be0; p.bes[1] = fbe; p.bes[2] = fbe + 128;
    p.ms[0]  = m0p; p.ms[1]  = fm;  p.ms[2]  = fm + 128;
    p.vvs[0] = v0p; p.vvs[1] = fv;  p.vvs[2] = fv + 128;
    p.vbb[0] = vbp; p.vbb[1] = vbp + 128;
    p.vgg[0] = vgp; p.vgg[1] = vgp + 128;
    p.vbt[0] = vbe; p.vbt[1] = vbe + 128;
    p.vmm[0] = vmp; p.vmm[1] = vmp + 128;
    p.vva[0] = vvp; p.vva[1] = vvp + 128;

    char* ws = (char*)d_ws;
    unsigned short* Vb0 = (unsigned short*)ws;                          // 8 MiB
    unsigned short* Vb1 = (unsigned short*)(ws + (size_t)(8 << 20));    // 8 MiB
    p.xb = (unsigned short*)(ws + (size_t)(16 << 20));                  // 8 MiB
    unsigned short* u   = (unsigned short*)(ws + (size_t)(24 << 20));   // packed weights
    for (int i = 0; i < 3; ++i) p.W1P[i] = u + i * 65536;
    for (int i = 0; i < 3; ++i) p.W2P[i] = u + 196608 + i * 65536;
    for (int i = 0; i < 2; ++i) p.VTP[i] = u + 393216 + i * 16384;
    p.xf = (float*)d_out;

    pack_weights<<<dim3(512), 256, 0, stream>>>(p);
    stage<1, -1, 0, 0, 0><<<dim3(1024), 256, 0, stream>>>(p, nullptr, Vb0);
    stage<0,  0, 1, 1, 0><<<dim3(1024), 256, 0, stream>>>(p, Vb0, Vb1);
    stage<0,  1, 2, -1, 1><<<dim3(1024), 256, 0, stream>>>(p, Vb1, nullptr);
}